// Round 3
// baseline (484.784 us; speedup 1.0000x reference)
//
#include <hip/hip_runtime.h>

#define NN 50000
#define NE 800000
#define NB 16384

#define NBKT 196          // buckets of 256 node ids (196*256 = 50176 >= NN)
#define BCAP 6144         // per-bucket capacity (mean 4081, sigma ~64)
#define CAPL 32           // LDS staging depth per bucket
#define FT   16           // flush threshold
#define P1_BLOCKS 512
#define P1_TILES  7       // 512*7*256 = 917504 >= NE

typedef unsigned int uint;

// ---------------- DNN GEMM + fused BN stats ------------------------------------
__global__ __launch_bounds__(256) void dnn_gemm(const float* __restrict__ X,
    const float* __restrict__ W, float* __restrict__ H,
    float* __restrict__ bnsum, float* __restrict__ bnsumsq)
{
    __shared__ float part[4][64 * 65];          // stride 65: conflict-free
    const int tid = threadIdx.x;
    const int lane = tid & 63;
    const int wv = __builtin_amdgcn_readfirstlane(tid >> 6);
    const int row = blockIdx.x * 64 + lane;
    float acc[64];
#pragma unroll
    for (int j = 0; j < 64; ++j) acc[j] = 0.f;
    const float4* xr = reinterpret_cast<const float4*>(X + (size_t)row * 256 + wv * 64);
    const float* Wb = W + wv * 64 * 64;
#pragma unroll 1
    for (int k4 = 0; k4 < 16; ++k4) {
        float4 xv = xr[k4];
        const float* wr = Wb + k4 * 4 * 64;
#pragma unroll
        for (int j = 0; j < 64; ++j) {
            float a = acc[j];
            a = fmaf(xv.x, wr[j],       a);
            a = fmaf(xv.y, wr[64 + j],  a);
            a = fmaf(xv.z, wr[128 + j], a);
            a = fmaf(xv.w, wr[192 + j], a);
            acc[j] = a;
        }
    }
#pragma unroll
    for (int j = 0; j < 64; ++j) part[wv][lane * 65 + j] = acc[j];
    __syncthreads();
    float s = 0.f, q = 0.f;
    for (int idx = tid; idx < 4096; idx += 256) {
        int r = idx >> 6, j = idx & 63;          // j == tid&63 (constant per thread)
        float v = part[0][r * 65 + j] + part[1][r * 65 + j] +
                  part[2][r * 65 + j] + part[3][r * 65 + j];
        H[(size_t)(blockIdx.x * 64 + r) * 64 + j] = v;
        s += v; q += v * v;
    }
    __syncthreads();
    float* red = &part[0][0];
    red[tid] = s; red[256 + tid] = q;
    __syncthreads();
    if (tid < 64) {
        atomicAdd(&bnsum[tid],  red[tid] + red[64+tid] + red[128+tid] + red[192+tid]);
        atomicAdd(&bnsumsq[tid], red[256+tid] + red[320+tid] + red[384+tid] + red[448+tid]);
    }
}

// ---------------- GCN1 GEMM: h1 = x2 @ gcn1_W ----------------------------------
__global__ __launch_bounds__(256) void gcn1_gemm(const float* __restrict__ X,
    const float* __restrict__ W, float* __restrict__ H)
{
    const int tid = threadIdx.x;
    const int lane = tid & 63;
    const int wv = __builtin_amdgcn_readfirstlane(tid >> 6);
    const int row = (blockIdx.x * 4 + wv) * 64 + lane;
    if (row >= NN) return;
    float acc[64];
#pragma unroll
    for (int j = 0; j < 64; ++j) acc[j] = 0.f;
    const float4* xr = reinterpret_cast<const float4*>(X + (size_t)row * 64);
#pragma unroll 1
    for (int k4 = 0; k4 < 16; ++k4) {
        float4 xv = xr[k4];
        const float* wr = W + k4 * 4 * 64;
#pragma unroll
        for (int j = 0; j < 64; ++j) {
            float a = acc[j];
            a = fmaf(xv.x, wr[j],       a);
            a = fmaf(xv.y, wr[64 + j],  a);
            a = fmaf(xv.z, wr[128 + j], a);
            a = fmaf(xv.w, wr[192 + j], a);
            acc[j] = a;
        }
    }
    float4* hr = reinterpret_cast<float4*>(H + (size_t)row * 64);
#pragma unroll
    for (int j4 = 0; j4 < 16; ++j4)
        hr[j4] = make_float4(acc[4*j4], acc[4*j4+1], acc[4*j4+2], acc[4*j4+3]);
}

// ---------------- pass1: LDS-staged dual binning (by col>>8 and row>>8) --------
// entC = (r<<8)|(c&255)  [24 bits]; entR = ((r&255)<<16)|c  [24 bits].
__global__ __launch_bounds__(256) void pass1_bin(const int* __restrict__ ei,
    uint* __restrict__ bufC, uint* __restrict__ bufR,
    int* __restrict__ gcurC, int* __restrict__ gcurR)
{
    __shared__ uint stC[NBKT * CAPL];
    __shared__ uint stR[NBKT * CAPL];
    __shared__ int lcC[NBKT], lcR[NBKT];
    const int tid = threadIdx.x;
    if (tid < NBKT) { lcC[tid] = 0; lcR[tid] = 0; }
    __syncthreads();
    const int base_e = blockIdx.x * (P1_TILES * 256);
    for (int t = 0; t < P1_TILES; ++t) {
        int e = base_e + t * 256 + tid;
        if (e < NE) {
            int r = ei[e], c = ei[NE + e];
            uint entC = ((uint)r << 8) | (uint)(c & 255);
            int b = c >> 8;
            int pos = atomicAdd(&lcC[b], 1);
            if (pos < CAPL) stC[b * CAPL + pos] = entC;
            else { int gp = atomicAdd(&gcurC[b], 1); bufC[(size_t)b * BCAP + gp] = entC; }
            uint entR = ((uint)(r & 255) << 16) | (uint)c;
            int rb = r >> 8;
            int pos2 = atomicAdd(&lcR[rb], 1);
            if (pos2 < CAPL) stR[rb * CAPL + pos2] = entR;
            else { int gp = atomicAdd(&gcurR[rb], 1); bufR[(size_t)rb * BCAP + gp] = entR; }
        }
        __syncthreads();
        const int thresh = (t == P1_TILES - 1) ? 1 : FT;
        if (tid < NBKT) {
            int n = lcC[tid]; if (n > CAPL) n = CAPL;
            if (n >= thresh) {
                int gb = atomicAdd(&gcurC[tid], n);
                uint* dst = bufC + (size_t)tid * BCAP + gb;
                for (int i = 0; i < n; ++i) dst[i] = stC[tid * CAPL + i];
                lcC[tid] = 0;
            }
            int n2 = lcR[tid]; if (n2 > CAPL) n2 = CAPL;
            if (n2 >= thresh) {
                int gb = atomicAdd(&gcurR[tid], n2);
                uint* dst = bufR + (size_t)tid * BCAP + gb;
                for (int i = 0; i < n2; ++i) dst[i] = stR[tid * CAPL + i];
                lcR[tid] = 0;
            }
        }
        __syncthreads();
    }
}

// ---------------- per-bucket in-degree histogram -> dis ------------------------
__global__ __launch_bounds__(256) void cnt_dis(const uint* __restrict__ bufC,
    const int* __restrict__ gcurC, float* __restrict__ dis)
{
    __shared__ int hist[256];
    const int tid = threadIdx.x, bb = blockIdx.x;
    hist[tid] = 0;
    __syncthreads();
    const int n = gcurC[bb];
    const uint* src = bufC + (size_t)bb * BCAP;
    for (int i = tid; i < n; i += 256) atomicAdd(&hist[src[i] & 255], 1);
    __syncthreads();
    int c = bb * 256 + tid;
    if (c < NN) dis[c] = rsqrtf((float)hist[tid] + 1.0f);
}

// ---------------- per-bucket wraw[r] = sum over out-edges of dis[col] ----------
__global__ __launch_bounds__(256) void wraw_pass(const uint* __restrict__ bufR,
    const int* __restrict__ gcurR, const float* __restrict__ dis,
    float* __restrict__ wraw)
{
    __shared__ float w[256];
    const int tid = threadIdx.x, rb = blockIdx.x;
    w[tid] = 0.f;
    __syncthreads();
    const int n = gcurR[rb];
    const uint* src = bufR + (size_t)rb * BCAP;
    for (int i = tid; i < n; i += 256) {
        uint e = src[i];
        atomicAdd(&w[e >> 16], dis[e & 0xffff]);
    }
    __syncthreads();
    int r = rb * 256 + tid;
    if (r < NN) wraw[r] = w[tid];
}

// ---------------- gather + fused node epilogue: svec += coef*relu(g) -----------
__global__ __launch_bounds__(256) void gather_pass(const uint* __restrict__ bufC,
    const int* __restrict__ gcurC, const float* __restrict__ dis,
    const float* __restrict__ wraw, const float* __restrict__ h1,
    const float* __restrict__ b1, float* __restrict__ svec)
{
    __shared__ float agg[256 * 64];             // 64 KiB
    const int tid = threadIdx.x;
    const int lane = tid & 63;
    const int wv = tid >> 6;
    const int bb = blockIdx.x;
    for (int i = tid; i < 256 * 64; i += 256) agg[i] = 0.f;
    __syncthreads();
    const int n = gcurC[bb];
    const uint* src = bufC + (size_t)bb * BCAP;
    for (int i0 = wv * 64; i0 < n; i0 += 256) {
        uint ent = 0;
        if (i0 + lane < n) ent = src[i0 + lane];
        int m = n - i0; if (m > 64) m = 64;
        if (m == 64) {
#pragma unroll
            for (int j = 0; j < 64; j += 4) {
                uint e0 = (uint)__builtin_amdgcn_readlane((int)ent, j);
                uint e1 = (uint)__builtin_amdgcn_readlane((int)ent, j + 1);
                uint e2 = (uint)__builtin_amdgcn_readlane((int)ent, j + 2);
                uint e3 = (uint)__builtin_amdgcn_readlane((int)ent, j + 3);
                float d0 = dis[e0 >> 8], d1 = dis[e1 >> 8];
                float d2 = dis[e2 >> 8], d3 = dis[e3 >> 8];
                float v0 = h1[(size_t)(e0 >> 8) * 64 + lane];
                float v1 = h1[(size_t)(e1 >> 8) * 64 + lane];
                float v2 = h1[(size_t)(e2 >> 8) * 64 + lane];
                float v3 = h1[(size_t)(e3 >> 8) * 64 + lane];
                atomicAdd(&agg[((e0 & 255) << 6) + lane], d0 * v0);
                atomicAdd(&agg[((e1 & 255) << 6) + lane], d1 * v1);
                atomicAdd(&agg[((e2 & 255) << 6) + lane], d2 * v2);
                atomicAdd(&agg[((e3 & 255) << 6) + lane], d3 * v3);
            }
        } else {
            for (int j = 0; j < m; ++j) {
                uint e0 = (uint)__builtin_amdgcn_readlane((int)ent, j);
                float d0 = dis[e0 >> 8];
                float v0 = h1[(size_t)(e0 >> 8) * 64 + lane];
                atomicAdd(&agg[((e0 & 255) << 6) + lane], d0 * v0);
            }
        }
    }
    __syncthreads();
    float sacc = 0.f;
    const float bl = b1[lane];
    for (int cl = wv; cl < 256; cl += 4) {
        int c = bb * 256 + cl;
        if (c >= NN) break;
        float d = dis[c];
        float g = fmaf(d, agg[(cl << 6) + lane],
                       fmaf(d * d, h1[(size_t)c * 64 + lane], bl));
        float coef = fmaf(d, wraw[c], d * d);
        sacc += coef * fmaxf(g, 0.f);
    }
    __syncthreads();
    agg[tid] = sacc;                            // reuse LDS for reduction
    __syncthreads();
    if (wv == 0)
        atomicAdd(&svec[lane], agg[lane] + agg[64 + lane] +
                               agg[128 + lane] + agg[192 + lane]);
}

// ---------------- finalize: BN scale/shift, gnn_emb, v_dnn, scalar const -------
__global__ void finalize_kernel(const float* __restrict__ bnsum,
    const float* __restrict__ bnsumsq, const float* __restrict__ gamma,
    const float* __restrict__ beta, const float* __restrict__ svec,
    const float* __restrict__ g2W, const float* __restrict__ g2b,
    const float* __restrict__ fc1W, const float* __restrict__ fc1b,
    const float* __restrict__ fc2W, const float* __restrict__ fc2b,
    float* __restrict__ scale, float* __restrict__ shift,
    float* __restrict__ vdnn, float* __restrict__ cons)
{
    int j = threadIdx.x;                         // 64 threads, 1 wave
    float mu = bnsum[j] * (1.0f / NB);
    float var = bnsumsq[j] * (1.0f / NB) - mu * mu;
    float sc = rsqrtf(var + 1e-5f) * gamma[j];
    scale[j] = sc;
    shift[j] = beta[j] - mu * sc;
    float ge = 0.f;
    for (int k = 0; k < 64; ++k) ge += svec[k] * g2W[k * 64 + j];
    ge = ge * (1.0f / NN) + g2b[j];
    float vd = 0.f, vg = 0.f;
    for (int k = 0; k < 64; ++k) {
        vd += fc1W[j * 64 + k] * fc2W[k];
        vg += fc1W[(64 + j) * 64 + k] * fc2W[k];
    }
    vdnn[j] = vd;
    float part = ge * vg + fc1b[j] * fc2W[j];
    for (int o = 32; o > 0; o >>= 1) part += __shfl_down(part, o);
    if (j == 0) cons[0] = part + fc2b[0];
}

// ---------------- output: out[i] = sum_j relu(h*sc+sh)*vdnn + C ----------------
__global__ __launch_bounds__(256) void out_kernel(const float* __restrict__ H,
    const float* __restrict__ scale, const float* __restrict__ shift,
    const float* __restrict__ vdnn, const float* __restrict__ cons,
    float* __restrict__ out)
{
    const int lane = threadIdx.x & 63;
    const int grp = threadIdx.x >> 6;
    const int i = blockIdx.x * 4 + grp;
    float x = H[(size_t)i * 64 + lane] * scale[lane] + shift[lane];
    x = fmaxf(x, 0.f) * vdnn[lane];
    for (int o = 32; o > 0; o >>= 1) x += __shfl_down(x, o);
    if (lane == 0) out[i] = x + cons[0];
}

extern "C" void kernel_launch(void* const* d_in, const int* in_sizes, int n_in,
                              void* d_out, int out_size, void* d_ws, size_t ws_size,
                              hipStream_t stream)
{
    const float* x1    = (const float*)d_in[0];
    const float* x2    = (const float*)d_in[1];
    const int*   ei    = (const int*)d_in[2];
    const float* dnnW  = (const float*)d_in[3];
    // d_in[4] = dnn_b: cancels inside BatchNorm, unused
    const float* gamma = (const float*)d_in[5];
    const float* beta  = (const float*)d_in[6];
    const float* g1W   = (const float*)d_in[7];
    const float* g1b   = (const float*)d_in[8];
    const float* g2W   = (const float*)d_in[9];
    const float* g2b   = (const float*)d_in[10];
    const float* fc1W  = (const float*)d_in[11];
    const float* fc1b  = (const float*)d_in[12];
    const float* fc2W  = (const float*)d_in[13];
    const float* fc2b  = (const float*)d_in[14];

    float* ws      = (float*)d_ws;
    float* h1      = ws;                          // 3,200,000 f
    float* hdnn    = h1 + 3200000;                // 1,048,576 f
    float* dis     = hdnn + 1048576;              // 50,176 f
    float* wraw    = dis + 50176;                 // 50,176 f
    uint*  bufC    = (uint*)(wraw + 50176);       // 196*6144 = 1,204,224
    uint*  bufR    = bufC + NBKT * BCAP;          // 1,204,224
    int*   gcurC   = (int*)(bufR + NBKT * BCAP);  // 256   <- zero region start
    int*   gcurR   = gcurC + 256;                 // 256
    float* bnsum   = (float*)(gcurR + 256);       // 64
    float* bnsumsq = bnsum + 64;                  // 64
    float* svec    = bnsumsq + 64;                // 64    <- zero region end
    float* scale   = svec + 64;
    float* shift   = scale + 64;
    float* vdnn    = shift + 64;
    float* cons    = vdnn + 64;

    hipMemsetAsync(gcurC, 0, (256 + 256 + 192) * sizeof(int), stream);

    dnn_gemm<<<256, 256, 0, stream>>>(x1, dnnW, hdnn, bnsum, bnsumsq);
    gcn1_gemm<<<196, 256, 0, stream>>>(x2, g1W, h1);
    pass1_bin<<<P1_BLOCKS, 256, 0, stream>>>(ei, bufC, bufR, gcurC, gcurR);
    cnt_dis<<<NBKT, 256, 0, stream>>>(bufC, gcurC, dis);
    wraw_pass<<<NBKT, 256, 0, stream>>>(bufR, gcurR, dis, wraw);
    gather_pass<<<NBKT, 256, 0, stream>>>(bufC, gcurC, dis, wraw, h1, g1b, svec);
    finalize_kernel<<<1, 64, 0, stream>>>(bnsum, bnsumsq, gamma, beta, svec,
                                          g2W, g2b, fc1W, fc1b, fc2W, fc2b,
                                          scale, shift, vdnn, cons);
    out_kernel<<<4096, 256, 0, stream>>>(hdnn, scale, shift, vdnn, cons,
                                         (float*)d_out);
}

// Round 4
// 466.763 us; speedup vs baseline: 1.0386x; 1.0386x over previous
//
#include <hip/hip_runtime.h>

#define NN 50000
#define NE 800000
#define NB 16384

#define NBKT 784          // buckets of 64 node ids (784*64 = 50176 >= NN)
#define BCAP 1280         // per-bucket capacity (mean 1020, sigma ~32)
#define CAPL 16           // LDS staging depth per bucket per binning block
#define P1B  128          // binning blocks -> mean 8 entries/bucket/block

typedef unsigned int uint;

// ---------------- DNN GEMM + fused BN stats ------------------------------------
__global__ __launch_bounds__(256) void dnn_gemm(const float* __restrict__ X,
    const float* __restrict__ W, float* __restrict__ H,
    float* __restrict__ bnsum, float* __restrict__ bnsumsq)
{
    __shared__ float part[4][64 * 65];          // stride 65: conflict-free
    const int tid = threadIdx.x;
    const int lane = tid & 63;
    const int wv = __builtin_amdgcn_readfirstlane(tid >> 6);
    const int row = blockIdx.x * 64 + lane;
    float acc[64];
#pragma unroll
    for (int j = 0; j < 64; ++j) acc[j] = 0.f;
    const float4* xr = reinterpret_cast<const float4*>(X + (size_t)row * 256 + wv * 64);
    const float* Wb = W + wv * 64 * 64;
#pragma unroll 1
    for (int k4 = 0; k4 < 16; ++k4) {
        float4 xv = xr[k4];
        const float* wr = Wb + k4 * 4 * 64;
#pragma unroll
        for (int j = 0; j < 64; ++j) {
            float a = acc[j];
            a = fmaf(xv.x, wr[j],       a);
            a = fmaf(xv.y, wr[64 + j],  a);
            a = fmaf(xv.z, wr[128 + j], a);
            a = fmaf(xv.w, wr[192 + j], a);
            acc[j] = a;
        }
    }
#pragma unroll
    for (int j = 0; j < 64; ++j) part[wv][lane * 65 + j] = acc[j];
    __syncthreads();
    float s = 0.f, q = 0.f;
    for (int idx = tid; idx < 4096; idx += 256) {
        int r = idx >> 6, j = idx & 63;
        float v = part[0][r * 65 + j] + part[1][r * 65 + j] +
                  part[2][r * 65 + j] + part[3][r * 65 + j];
        H[(size_t)(blockIdx.x * 64 + r) * 64 + j] = v;
        s += v; q += v * v;
    }
    __syncthreads();
    float* red = &part[0][0];
    red[tid] = s; red[256 + tid] = q;
    __syncthreads();
    if (tid < 64) {
        atomicAdd(&bnsum[tid],  red[tid] + red[64+tid] + red[128+tid] + red[192+tid]);
        atomicAdd(&bnsumsq[tid], red[256+tid] + red[320+tid] + red[384+tid] + red[448+tid]);
    }
}

// ---------------- GCN1 GEMM (dis-scaled): h1d = dis[row] * (x2 @ gcn1_W) -------
__global__ __launch_bounds__(256) void gcn1_gemm(const float* __restrict__ X,
    const float* __restrict__ W, const float* __restrict__ dis,
    float* __restrict__ H)
{
    const int tid = threadIdx.x;
    const int lane = tid & 63;
    const int wv = __builtin_amdgcn_readfirstlane(tid >> 6);
    const int row = (blockIdx.x * 4 + wv) * 64 + lane;
    if (row >= NN) return;
    float acc[64];
#pragma unroll
    for (int j = 0; j < 64; ++j) acc[j] = 0.f;
    const float4* xr = reinterpret_cast<const float4*>(X + (size_t)row * 64);
#pragma unroll 1
    for (int k4 = 0; k4 < 16; ++k4) {
        float4 xv = xr[k4];
        const float* wr = W + k4 * 4 * 64;
#pragma unroll
        for (int j = 0; j < 64; ++j) {
            float a = acc[j];
            a = fmaf(xv.x, wr[j],       a);
            a = fmaf(xv.y, wr[64 + j],  a);
            a = fmaf(xv.z, wr[128 + j], a);
            a = fmaf(xv.w, wr[192 + j], a);
            acc[j] = a;
        }
    }
    const float d = dis[row];
    float4* hr = reinterpret_cast<float4*>(H + (size_t)row * 64);
#pragma unroll
    for (int j4 = 0; j4 < 16; ++j4)
        hr[j4] = make_float4(d*acc[4*j4], d*acc[4*j4+1], d*acc[4*j4+2], d*acc[4*j4+3]);
}

// ---------------- bin by col>>6: ent = (r<<6)|(c&63) ---------------------------
__global__ __launch_bounds__(256) void binC(const int* __restrict__ ei,
    uint* __restrict__ buf, int* __restrict__ gcur)
{
    __shared__ uint st[NBKT * CAPL];            // 50,176 B
    __shared__ int lc[NBKT];
    const int tid = threadIdx.x;
    for (int i = tid; i < NBKT; i += 256) lc[i] = 0;
    __syncthreads();
    const int per = (NE + P1B - 1) / P1B;
    const int lo = blockIdx.x * per;
    const int hi = (lo + per < NE) ? lo + per : NE;
    for (int e = lo + tid; e < hi; e += 256) {
        int r = ei[e], c = ei[NE + e];
        uint ent = ((uint)r << 6) | (uint)(c & 63);
        int b = c >> 6;
        int pos = atomicAdd(&lc[b], 1);
        if (pos < CAPL) st[b * CAPL + pos] = ent;
        else { int gp = atomicAdd(&gcur[b], 1); buf[(size_t)b * BCAP + gp] = ent; }
    }
    __syncthreads();
    for (int b = tid; b < NBKT; b += 256) {
        int n = lc[b]; if (n > CAPL) n = CAPL;
        if (n) {
            int gb = atomicAdd(&gcur[b], n);
            uint* dst = buf + (size_t)b * BCAP + gb;
            for (int i = 0; i < n; ++i) dst[i] = st[b * CAPL + i];
        }
    }
}

// ---------------- bin by row>>6: ent = ((r&63)<<16)|c --------------------------
__global__ __launch_bounds__(256) void binR(const int* __restrict__ ei,
    uint* __restrict__ buf, int* __restrict__ gcur)
{
    __shared__ uint st[NBKT * CAPL];
    __shared__ int lc[NBKT];
    const int tid = threadIdx.x;
    for (int i = tid; i < NBKT; i += 256) lc[i] = 0;
    __syncthreads();
    const int per = (NE + P1B - 1) / P1B;
    const int lo = blockIdx.x * per;
    const int hi = (lo + per < NE) ? lo + per : NE;
    for (int e = lo + tid; e < hi; e += 256) {
        int r = ei[e], c = ei[NE + e];
        uint ent = ((uint)(r & 63) << 16) | (uint)c;
        int b = r >> 6;
        int pos = atomicAdd(&lc[b], 1);
        if (pos < CAPL) st[b * CAPL + pos] = ent;
        else { int gp = atomicAdd(&gcur[b], 1); buf[(size_t)b * BCAP + gp] = ent; }
    }
    __syncthreads();
    for (int b = tid; b < NBKT; b += 256) {
        int n = lc[b]; if (n > CAPL) n = CAPL;
        if (n) {
            int gb = atomicAdd(&gcur[b], n);
            uint* dst = buf + (size_t)b * BCAP + gb;
            for (int i = 0; i < n; ++i) dst[i] = st[b * CAPL + i];
        }
    }
}

// ---------------- per-bucket in-degree histogram -> dis ------------------------
__global__ __launch_bounds__(256) void cnt_dis(const uint* __restrict__ bufC,
    const int* __restrict__ gcurC, float* __restrict__ dis)
{
    __shared__ int hist[64];
    const int tid = threadIdx.x, bb = blockIdx.x;
    if (tid < 64) hist[tid] = 0;
    __syncthreads();
    const int n = gcurC[bb];
    const uint* src = bufC + (size_t)bb * BCAP;
    for (int i = tid; i < n; i += 256) atomicAdd(&hist[src[i] & 63], 1);
    __syncthreads();
    if (tid < 64) {
        int c = bb * 64 + tid;
        if (c < NN) dis[c] = rsqrtf((float)hist[tid] + 1.0f);
    }
}

// ---------------- per-bucket wraw[r] = sum over out-edges of dis[col] ----------
__global__ __launch_bounds__(256) void wraw_pass(const uint* __restrict__ bufR,
    const int* __restrict__ gcurR, const float* __restrict__ dis,
    float* __restrict__ wraw)
{
    __shared__ float w[64];
    const int tid = threadIdx.x, rb = blockIdx.x;
    if (tid < 64) w[tid] = 0.f;
    __syncthreads();
    const int n = gcurR[rb];
    const uint* src = bufR + (size_t)rb * BCAP;
    for (int i = tid; i < n; i += 256) {
        uint e = src[i];
        atomicAdd(&w[e >> 16], dis[e & 0xffff]);
    }
    __syncthreads();
    if (tid < 64) {
        int r = rb * 64 + tid;
        if (r < NN) wraw[r] = w[tid];
    }
}

// ---------------- gather + fused node epilogue: svec += coef*relu(g) -----------
// g_c = dis_c*(sum_in h1d_r + h1d_c) + b1 ; coef_c = dis_c*wraw_c + dis_c^2
__global__ __launch_bounds__(256) void gather_pass(const uint* __restrict__ bufC,
    const int* __restrict__ gcurC, const float* __restrict__ dis,
    const float* __restrict__ wraw, const float* __restrict__ h1d,
    const float* __restrict__ b1, float* __restrict__ svec)
{
    __shared__ float agg[64 * 64];              // 16 KiB
    const int tid = threadIdx.x;
    const int lane = tid & 63;
    const int wv = tid >> 6;
    const int bb = blockIdx.x;
    for (int i = tid; i < 64 * 64; i += 256) agg[i] = 0.f;
    __syncthreads();
    const int n = gcurC[bb];
    const uint* src = bufC + (size_t)bb * BCAP;
    for (int i0 = wv * 64; i0 < n; i0 += 256) {
        uint ent = (i0 + lane < n) ? src[i0 + lane] : 0u;
        int m = n - i0; if (m > 64) m = 64;
        if (m == 64) {
#pragma unroll
            for (int j = 0; j < 64; j += 8) {
                uint e0 = (uint)__builtin_amdgcn_readlane((int)ent, j);
                uint e1 = (uint)__builtin_amdgcn_readlane((int)ent, j + 1);
                uint e2 = (uint)__builtin_amdgcn_readlane((int)ent, j + 2);
                uint e3 = (uint)__builtin_amdgcn_readlane((int)ent, j + 3);
                uint e4 = (uint)__builtin_amdgcn_readlane((int)ent, j + 4);
                uint e5 = (uint)__builtin_amdgcn_readlane((int)ent, j + 5);
                uint e6 = (uint)__builtin_amdgcn_readlane((int)ent, j + 6);
                uint e7 = (uint)__builtin_amdgcn_readlane((int)ent, j + 7);
                // h1d address: (e>>6)*64 + lane == (e & ~63) + lane
                float v0 = h1d[(size_t)(e0 & ~63u) + lane];
                float v1 = h1d[(size_t)(e1 & ~63u) + lane];
                float v2 = h1d[(size_t)(e2 & ~63u) + lane];
                float v3 = h1d[(size_t)(e3 & ~63u) + lane];
                float v4 = h1d[(size_t)(e4 & ~63u) + lane];
                float v5 = h1d[(size_t)(e5 & ~63u) + lane];
                float v6 = h1d[(size_t)(e6 & ~63u) + lane];
                float v7 = h1d[(size_t)(e7 & ~63u) + lane];
                atomicAdd(&agg[((e0 & 63u) << 6) + lane], v0);
                atomicAdd(&agg[((e1 & 63u) << 6) + lane], v1);
                atomicAdd(&agg[((e2 & 63u) << 6) + lane], v2);
                atomicAdd(&agg[((e3 & 63u) << 6) + lane], v3);
                atomicAdd(&agg[((e4 & 63u) << 6) + lane], v4);
                atomicAdd(&agg[((e5 & 63u) << 6) + lane], v5);
                atomicAdd(&agg[((e6 & 63u) << 6) + lane], v6);
                atomicAdd(&agg[((e7 & 63u) << 6) + lane], v7);
            }
        } else {
            for (int j = 0; j < m; ++j) {
                uint e0 = (uint)__builtin_amdgcn_readlane((int)ent, j);
                float v0 = h1d[(size_t)(e0 & ~63u) + lane];
                atomicAdd(&agg[((e0 & 63u) << 6) + lane], v0);
            }
        }
    }
    __syncthreads();
    float sacc = 0.f;
    const float bl = b1[lane];
    for (int cl = wv; cl < 64; cl += 4) {
        int c = bb * 64 + cl;
        if (c >= NN) break;
        float d = dis[c];
        float g = fmaf(d, agg[(cl << 6) + lane] + h1d[(size_t)c * 64 + lane], bl);
        float coef = fmaf(d, wraw[c], d * d);
        sacc += coef * fmaxf(g, 0.f);
    }
    __syncthreads();
    agg[tid] = sacc;                            // reuse LDS for reduction
    __syncthreads();
    if (wv == 0)
        atomicAdd(&svec[lane], agg[lane] + agg[64 + lane] +
                               agg[128 + lane] + agg[192 + lane]);
}

// ---------------- finalize: BN scale/shift, gnn_emb, v_dnn, scalar const -------
__global__ void finalize_kernel(const float* __restrict__ bnsum,
    const float* __restrict__ bnsumsq, const float* __restrict__ gamma,
    const float* __restrict__ beta, const float* __restrict__ svec,
    const float* __restrict__ g2W, const float* __restrict__ g2b,
    const float* __restrict__ fc1W, const float* __restrict__ fc1b,
    const float* __restrict__ fc2W, const float* __restrict__ fc2b,
    float* __restrict__ scale, float* __restrict__ shift,
    float* __restrict__ vdnn, float* __restrict__ cons)
{
    int j = threadIdx.x;                         // 64 threads, 1 wave
    float mu = bnsum[j] * (1.0f / NB);
    float var = bnsumsq[j] * (1.0f / NB) - mu * mu;
    float sc = rsqrtf(var + 1e-5f) * gamma[j];
    scale[j] = sc;
    shift[j] = beta[j] - mu * sc;
    float ge = 0.f;
    for (int k = 0; k < 64; ++k) ge += svec[k] * g2W[k * 64 + j];
    ge = ge * (1.0f / NN) + g2b[j];
    float vd = 0.f, vg = 0.f;
    for (int k = 0; k < 64; ++k) {
        vd += fc1W[j * 64 + k] * fc2W[k];
        vg += fc1W[(64 + j) * 64 + k] * fc2W[k];
    }
    vdnn[j] = vd;
    float part = ge * vg + fc1b[j] * fc2W[j];
    for (int o = 32; o > 0; o >>= 1) part += __shfl_down(part, o);
    if (j == 0) cons[0] = part + fc2b[0];
}

// ---------------- output: out[i] = sum_j relu(h*sc+sh)*vdnn + C ----------------
__global__ __launch_bounds__(256) void out_kernel(const float* __restrict__ H,
    const float* __restrict__ scale, const float* __restrict__ shift,
    const float* __restrict__ vdnn, const float* __restrict__ cons,
    float* __restrict__ out)
{
    const int lane = threadIdx.x & 63;
    const int grp = threadIdx.x >> 6;
    const int i = blockIdx.x * 4 + grp;
    float x = H[(size_t)i * 64 + lane] * scale[lane] + shift[lane];
    x = fmaxf(x, 0.f) * vdnn[lane];
    for (int o = 32; o > 0; o >>= 1) x += __shfl_down(x, o);
    if (lane == 0) out[i] = x + cons[0];
}

extern "C" void kernel_launch(void* const* d_in, const int* in_sizes, int n_in,
                              void* d_out, int out_size, void* d_ws, size_t ws_size,
                              hipStream_t stream)
{
    const float* x1    = (const float*)d_in[0];
    const float* x2    = (const float*)d_in[1];
    const int*   ei    = (const int*)d_in[2];
    const float* dnnW  = (const float*)d_in[3];
    // d_in[4] = dnn_b: cancels inside BatchNorm, unused
    const float* gamma = (const float*)d_in[5];
    const float* beta  = (const float*)d_in[6];
    const float* g1W   = (const float*)d_in[7];
    const float* g1b   = (const float*)d_in[8];
    const float* g2W   = (const float*)d_in[9];
    const float* g2b   = (const float*)d_in[10];
    const float* fc1W  = (const float*)d_in[11];
    const float* fc1b  = (const float*)d_in[12];
    const float* fc2W  = (const float*)d_in[13];
    const float* fc2b  = (const float*)d_in[14];

    float* ws      = (float*)d_ws;
    float* h1d     = ws;                          // 3,200,000 f
    float* hdnn    = h1d + 3200000;               // 1,048,576 f
    float* dis     = hdnn + 1048576;              // 50,176 f
    float* wraw    = dis + 50176;                 // 50,176 f
    uint*  bufC    = (uint*)(wraw + 50176);       // 784*1280 = 1,003,520
    uint*  bufR    = bufC + NBKT * BCAP;          // 1,003,520
    int*   gcurC   = (int*)(bufR + NBKT * BCAP);  // 784   <- zero region start
    int*   gcurR   = gcurC + NBKT;                // 784
    float* bnsum   = (float*)(gcurR + NBKT);      // 64
    float* bnsumsq = bnsum + 64;                  // 64
    float* svec    = bnsumsq + 64;                // 64    <- zero region end
    float* scale   = svec + 64;
    float* shift   = scale + 64;
    float* vdnn    = shift + 64;
    float* cons    = vdnn + 64;

    hipMemsetAsync(gcurC, 0, (NBKT * 2 + 192) * sizeof(int), stream);

    dnn_gemm<<<256, 256, 0, stream>>>(x1, dnnW, hdnn, bnsum, bnsumsq);
    binC<<<P1B, 256, 0, stream>>>(ei, bufC, gcurC);
    binR<<<P1B, 256, 0, stream>>>(ei, bufR, gcurR);
    cnt_dis<<<NBKT, 256, 0, stream>>>(bufC, gcurC, dis);
    gcn1_gemm<<<196, 256, 0, stream>>>(x2, g1W, dis, h1d);
    wraw_pass<<<NBKT, 256, 0, stream>>>(bufR, gcurR, dis, wraw);
    gather_pass<<<NBKT, 256, 0, stream>>>(bufC, gcurC, dis, wraw, h1d, g1b, svec);
    finalize_kernel<<<1, 64, 0, stream>>>(bnsum, bnsumsq, gamma, beta, svec,
                                          g2W, g2b, fc1W, fc1b, fc2W, fc2b,
                                          scale, shift, vdnn, cons);
    out_kernel<<<4096, 256, 0, stream>>>(hdnn, scale, shift, vdnn, cons,
                                         (float*)d_out);
}

// Round 5
// 164.609 us; speedup vs baseline: 2.9451x; 2.8356x over previous
//
#include <hip/hip_runtime.h>

#define NN 50000
#define NE 800000
#define NB 16384

#define NBKT 784          // buckets of 64 node ids (784*64 = 50176 >= NN)
#define BCAP 1280         // per-bucket capacity (mean 1020, +8 sigma)
#define CAPL 16           // LDS staging depth per bucket per binning block
#define P1B  128          // binning blocks -> mean 8 entries/bucket/block

typedef unsigned int uint;

// ---------------- DNN GEMM + fused BN stats ------------------------------------
__global__ __launch_bounds__(256) void dnn_gemm(const float* __restrict__ X,
    const float* __restrict__ W, float* __restrict__ H,
    float* __restrict__ bnsum, float* __restrict__ bnsumsq)
{
    __shared__ float part[4][64 * 65];          // stride 65: conflict-free
    const int tid = threadIdx.x;
    const int lane = tid & 63;
    const int wv = __builtin_amdgcn_readfirstlane(tid >> 6);
    const int row = blockIdx.x * 64 + lane;
    float acc[64];
#pragma unroll
    for (int j = 0; j < 64; ++j) acc[j] = 0.f;
    const float4* xr = reinterpret_cast<const float4*>(X + (size_t)row * 256 + wv * 64);
    const float* Wb = W + wv * 64 * 64;
#pragma unroll 1
    for (int k4 = 0; k4 < 16; ++k4) {
        float4 xv = xr[k4];
        const float* wr = Wb + k4 * 4 * 64;
#pragma unroll
        for (int j = 0; j < 64; ++j) {
            float a = acc[j];
            a = fmaf(xv.x, wr[j],       a);
            a = fmaf(xv.y, wr[64 + j],  a);
            a = fmaf(xv.z, wr[128 + j], a);
            a = fmaf(xv.w, wr[192 + j], a);
            acc[j] = a;
        }
    }
#pragma unroll
    for (int j = 0; j < 64; ++j) part[wv][lane * 65 + j] = acc[j];
    __syncthreads();
    float s = 0.f, q = 0.f;
    for (int idx = tid; idx < 4096; idx += 256) {
        int r = idx >> 6, j = idx & 63;
        float v = part[0][r * 65 + j] + part[1][r * 65 + j] +
                  part[2][r * 65 + j] + part[3][r * 65 + j];
        H[(size_t)(blockIdx.x * 64 + r) * 64 + j] = v;
        s += v; q += v * v;
    }
    __syncthreads();
    float* red = &part[0][0];
    red[tid] = s; red[256 + tid] = q;
    __syncthreads();
    if (tid < 64) {
        atomicAdd(&bnsum[tid],  red[tid] + red[64+tid] + red[128+tid] + red[192+tid]);
        atomicAdd(&bnsumsq[tid], red[256+tid] + red[320+tid] + red[384+tid] + red[448+tid]);
    }
}

// ---------------- GCN1 GEMM (dis-scaled): h1d = dis[row] * (x2 @ gcn1_W) -------
__global__ __launch_bounds__(256) void gcn1_gemm(const float* __restrict__ X,
    const float* __restrict__ W, const float* __restrict__ dis,
    float* __restrict__ H)
{
    const int tid = threadIdx.x;
    const int lane = tid & 63;
    const int wv = __builtin_amdgcn_readfirstlane(tid >> 6);
    const int row = (blockIdx.x * 4 + wv) * 64 + lane;
    if (row >= NN) return;
    float acc[64];
#pragma unroll
    for (int j = 0; j < 64; ++j) acc[j] = 0.f;
    const float4* xr = reinterpret_cast<const float4*>(X + (size_t)row * 64);
#pragma unroll 1
    for (int k4 = 0; k4 < 16; ++k4) {
        float4 xv = xr[k4];
        const float* wr = W + k4 * 4 * 64;
#pragma unroll
        for (int j = 0; j < 64; ++j) {
            float a = acc[j];
            a = fmaf(xv.x, wr[j],       a);
            a = fmaf(xv.y, wr[64 + j],  a);
            a = fmaf(xv.z, wr[128 + j], a);
            a = fmaf(xv.w, wr[192 + j], a);
            acc[j] = a;
        }
    }
    const float d = dis[row];
    float4* hr = reinterpret_cast<float4*>(H + (size_t)row * 64);
#pragma unroll
    for (int j4 = 0; j4 < 16; ++j4)
        hr[j4] = make_float4(d*acc[4*j4], d*acc[4*j4+1], d*acc[4*j4+2], d*acc[4*j4+3]);
}

// ---------------- bin by col>>6: ent = (r<<6)|(c&63) ---------------------------
__global__ __launch_bounds__(256) void binC(const int* __restrict__ ei,
    uint* __restrict__ buf, int* __restrict__ gcur)
{
    __shared__ uint st[NBKT * CAPL];            // 50,176 B
    __shared__ int lc[NBKT];
    const int tid = threadIdx.x;
    for (int i = tid; i < NBKT; i += 256) lc[i] = 0;
    __syncthreads();
    const int per = (NE + P1B - 1) / P1B;
    const int lo = blockIdx.x * per;
    const int hi = (lo + per < NE) ? lo + per : NE;
    for (int e = lo + tid; e < hi; e += 256) {
        int r = ei[e], c = ei[NE + e];
        uint ent = ((uint)r << 6) | (uint)(c & 63);
        int b = c >> 6;
        int pos = atomicAdd(&lc[b], 1);
        if (pos < CAPL) st[b * CAPL + pos] = ent;
        else { int gp = atomicAdd(&gcur[b], 1); buf[(size_t)b * BCAP + gp] = ent; }
    }
    __syncthreads();
    for (int b = tid; b < NBKT; b += 256) {
        int n = lc[b]; if (n > CAPL) n = CAPL;
        if (n) {
            int gb = atomicAdd(&gcur[b], n);
            uint* dst = buf + (size_t)b * BCAP + gb;
            for (int i = 0; i < n; ++i) dst[i] = st[b * CAPL + i];
        }
    }
}

// ---------------- bin by row>>6: ent = ((r&63)<<16)|c --------------------------
__global__ __launch_bounds__(256) void binR(const int* __restrict__ ei,
    uint* __restrict__ buf, int* __restrict__ gcur)
{
    __shared__ uint st[NBKT * CAPL];
    __shared__ int lc[NBKT];
    const int tid = threadIdx.x;
    for (int i = tid; i < NBKT; i += 256) lc[i] = 0;
    __syncthreads();
    const int per = (NE + P1B - 1) / P1B;
    const int lo = blockIdx.x * per;
    const int hi = (lo + per < NE) ? lo + per : NE;
    for (int e = lo + tid; e < hi; e += 256) {
        int r = ei[e], c = ei[NE + e];
        uint ent = ((uint)(r & 63) << 16) | (uint)c;
        int b = r >> 6;
        int pos = atomicAdd(&lc[b], 1);
        if (pos < CAPL) st[b * CAPL + pos] = ent;
        else { int gp = atomicAdd(&gcur[b], 1); buf[(size_t)b * BCAP + gp] = ent; }
    }
    __syncthreads();
    for (int b = tid; b < NBKT; b += 256) {
        int n = lc[b]; if (n > CAPL) n = CAPL;
        if (n) {
            int gb = atomicAdd(&gcur[b], n);
            uint* dst = buf + (size_t)b * BCAP + gb;
            for (int i = 0; i < n; ++i) dst[i] = st[b * CAPL + i];
        }
    }
}

// ---------------- per-bucket in-degree histogram -> dis ------------------------
__global__ __launch_bounds__(256) void cnt_dis(const uint* __restrict__ bufC,
    const int* __restrict__ gcurC, float* __restrict__ dis)
{
    __shared__ int hist[64];
    const int tid = threadIdx.x, bb = blockIdx.x;
    if (tid < 64) hist[tid] = 0;
    __syncthreads();
    const int n = gcurC[bb];
    const uint* src = bufC + (size_t)bb * BCAP;
    for (int i = tid; i < n; i += 256) atomicAdd(&hist[src[i] & 63], 1);
    __syncthreads();
    if (tid < 64) {
        int c = bb * 64 + tid;
        if (c < NN) dis[c] = rsqrtf((float)hist[tid] + 1.0f);
    }
}

// ---------------- per-bucket wraw[r] = sum over out-edges of dis[col] ----------
__global__ __launch_bounds__(256) void wraw_pass(const uint* __restrict__ bufR,
    const int* __restrict__ gcurR, const float* __restrict__ dis,
    float* __restrict__ wraw)
{
    __shared__ float w[64];
    const int tid = threadIdx.x, rb = blockIdx.x;
    if (tid < 64) w[tid] = 0.f;
    __syncthreads();
    const int n = gcurR[rb];
    const uint* src = bufR + (size_t)rb * BCAP;
    for (int i = tid; i < n; i += 256) {
        uint e = src[i];
        atomicAdd(&w[e >> 16], dis[e & 0xffff]);
    }
    __syncthreads();
    if (tid < 64) {
        int r = rb * 64 + tid;
        if (r < NN) wraw[r] = w[tid];
    }
}

// ---------------- gather: LDS counting-sort + register-accum per node ----------
// g_c = dis_c*(sum_in h1d_r + h1d_c) + b1 ; coef_c = dis_c*wraw_c + dis_c^2
__global__ __launch_bounds__(256) void gather_pass(const uint* __restrict__ bufC,
    const int* __restrict__ gcurC, const float* __restrict__ dis,
    const float* __restrict__ wraw, const float* __restrict__ h1d,
    const float* __restrict__ b1, float* __restrict__ svec)
{
    __shared__ int sorted[BCAP];
    __shared__ int cntS[64], offsS[64], curS[64];
    __shared__ float red[4][64];
    const int tid = threadIdx.x;
    const int lane = tid & 63;
    const int wv = __builtin_amdgcn_readfirstlane(tid >> 6);
    const int bb = blockIdx.x;
    if (tid < 64) cntS[tid] = 0;
    __syncthreads();
    const int n = gcurC[bb];
    const uint* src = bufC + (size_t)bb * BCAP;
    for (int i = tid; i < n; i += 256)
        atomicAdd(&cntS[src[i] & 63u], 1);
    __syncthreads();
    if (tid < 64) {                              // wave 0: 64-wide shfl scan
        int v = cntS[tid];
        int s = v;
#pragma unroll
        for (int o = 1; o < 64; o <<= 1) {
            int u = __shfl_up(s, o);
            if (lane >= o) s += u;
        }
        offsS[tid] = s - v;
        curS[tid] = s - v;
    }
    __syncthreads();
    for (int i = tid; i < n; i += 256) {         // LDS scatter into sorted order
        uint e = src[i];
        int p = atomicAdd(&curS[e & 63u], 1);
        sorted[p] = (int)(e >> 6);
    }
    __syncthreads();
    // each wave: 16 consecutive nodes, register accumulation, 8-deep load ILP
    float sacc = 0.f;
    const float bl = b1[lane];
#pragma unroll 1
    for (int t = 0; t < 16; ++t) {
        const int nd = wv * 16 + t;
        const int lo = offsS[nd], hi = lo + cntS[nd];
        float acc = 0.f;
        int e = lo;
        for (; e + 8 <= hi; e += 8) {
            int r0 = sorted[e],     r1 = sorted[e + 1];
            int r2 = sorted[e + 2], r3 = sorted[e + 3];
            int r4 = sorted[e + 4], r5 = sorted[e + 5];
            int r6 = sorted[e + 6], r7 = sorted[e + 7];
            float v0 = h1d[(size_t)r0 * 64 + lane];
            float v1 = h1d[(size_t)r1 * 64 + lane];
            float v2 = h1d[(size_t)r2 * 64 + lane];
            float v3 = h1d[(size_t)r3 * 64 + lane];
            float v4 = h1d[(size_t)r4 * 64 + lane];
            float v5 = h1d[(size_t)r5 * 64 + lane];
            float v6 = h1d[(size_t)r6 * 64 + lane];
            float v7 = h1d[(size_t)r7 * 64 + lane];
            acc += ((v0 + v1) + (v2 + v3)) + ((v4 + v5) + (v6 + v7));
        }
        for (; e + 2 <= hi; e += 2) {
            int r0 = sorted[e], r1 = sorted[e + 1];
            float v0 = h1d[(size_t)r0 * 64 + lane];
            float v1 = h1d[(size_t)r1 * 64 + lane];
            acc += v0 + v1;
        }
        if (e < hi) acc += h1d[(size_t)sorted[e] * 64 + lane];
        const int c = bb * 64 + nd;
        if (c < NN) {
            float d = dis[c];
            float g = fmaf(d, acc + h1d[(size_t)c * 64 + lane], bl);
            float coef = fmaf(d, wraw[c], d * d);
            sacc += coef * fmaxf(g, 0.f);
        }
    }
    red[wv][lane] = sacc;
    __syncthreads();
    if (wv == 0)
        atomicAdd(&svec[lane], red[0][lane] + red[1][lane] +
                               red[2][lane] + red[3][lane]);
}

// ---------------- finalize: BN scale/shift, gnn_emb, v_dnn, scalar const -------
__global__ void finalize_kernel(const float* __restrict__ bnsum,
    const float* __restrict__ bnsumsq, const float* __restrict__ gamma,
    const float* __restrict__ beta, const float* __restrict__ svec,
    const float* __restrict__ g2W, const float* __restrict__ g2b,
    const float* __restrict__ fc1W, const float* __restrict__ fc1b,
    const float* __restrict__ fc2W, const float* __restrict__ fc2b,
    float* __restrict__ scale, float* __restrict__ shift,
    float* __restrict__ vdnn, float* __restrict__ cons)
{
    int j = threadIdx.x;                         // 64 threads, 1 wave
    float mu = bnsum[j] * (1.0f / NB);
    float var = bnsumsq[j] * (1.0f / NB) - mu * mu;
    float sc = rsqrtf(var + 1e-5f) * gamma[j];
    scale[j] = sc;
    shift[j] = beta[j] - mu * sc;
    float ge = 0.f;
    for (int k = 0; k < 64; ++k) ge += svec[k] * g2W[k * 64 + j];
    ge = ge * (1.0f / NN) + g2b[j];
    float vd = 0.f, vg = 0.f;
    for (int k = 0; k < 64; ++k) {
        vd += fc1W[j * 64 + k] * fc2W[k];
        vg += fc1W[(64 + j) * 64 + k] * fc2W[k];
    }
    vdnn[j] = vd;
    float part = ge * vg + fc1b[j] * fc2W[j];
    for (int o = 32; o > 0; o >>= 1) part += __shfl_down(part, o);
    if (j == 0) cons[0] = part + fc2b[0];
}

// ---------------- output: out[i] = sum_j relu(h*sc+sh)*vdnn + C ----------------
__global__ __launch_bounds__(256) void out_kernel(const float* __restrict__ H,
    const float* __restrict__ scale, const float* __restrict__ shift,
    const float* __restrict__ vdnn, const float* __restrict__ cons,
    float* __restrict__ out)
{
    const int lane = threadIdx.x & 63;
    const int grp = threadIdx.x >> 6;
    const int i = blockIdx.x * 4 + grp;
    float x = H[(size_t)i * 64 + lane] * scale[lane] + shift[lane];
    x = fmaxf(x, 0.f) * vdnn[lane];
    for (int o = 32; o > 0; o >>= 1) x += __shfl_down(x, o);
    if (lane == 0) out[i] = x + cons[0];
}

extern "C" void kernel_launch(void* const* d_in, const int* in_sizes, int n_in,
                              void* d_out, int out_size, void* d_ws, size_t ws_size,
                              hipStream_t stream)
{
    const float* x1    = (const float*)d_in[0];
    const float* x2    = (const float*)d_in[1];
    const int*   ei    = (const int*)d_in[2];
    const float* dnnW  = (const float*)d_in[3];
    // d_in[4] = dnn_b: cancels inside BatchNorm, unused
    const float* gamma = (const float*)d_in[5];
    const float* beta  = (const float*)d_in[6];
    const float* g1W   = (const float*)d_in[7];
    const float* g1b   = (const float*)d_in[8];
    const float* g2W   = (const float*)d_in[9];
    const float* g2b   = (const float*)d_in[10];
    const float* fc1W  = (const float*)d_in[11];
    const float* fc1b  = (const float*)d_in[12];
    const float* fc2W  = (const float*)d_in[13];
    const float* fc2b  = (const float*)d_in[14];

    float* ws      = (float*)d_ws;
    float* h1d     = ws;                          // 3,200,000 f
    float* hdnn    = h1d + 3200000;               // 1,048,576 f
    float* dis     = hdnn + 1048576;              // 50,176 f
    float* wraw    = dis + 50176;                 // 50,176 f
    uint*  bufC    = (uint*)(wraw + 50176);       // 784*1280 = 1,003,520
    uint*  bufR    = bufC + NBKT * BCAP;          // 1,003,520
    int*   gcurC   = (int*)(bufR + NBKT * BCAP);  // 784   <- zero region start
    int*   gcurR   = gcurC + NBKT;                // 784
    float* bnsum   = (float*)(gcurR + NBKT);      // 64
    float* bnsumsq = bnsum + 64;                  // 64
    float* svec    = bnsumsq + 64;                // 64    <- zero region end
    float* scale   = svec + 64;
    float* shift   = scale + 64;
    float* vdnn    = shift + 64;
    float* cons    = vdnn + 64;

    hipMemsetAsync(gcurC, 0, (NBKT * 2 + 192) * sizeof(int), stream);

    dnn_gemm<<<256, 256, 0, stream>>>(x1, dnnW, hdnn, bnsum, bnsumsq);
    binC<<<P1B, 256, 0, stream>>>(ei, bufC, gcurC);
    binR<<<P1B, 256, 0, stream>>>(ei, bufR, gcurR);
    cnt_dis<<<NBKT, 256, 0, stream>>>(bufC, gcurC, dis);
    gcn1_gemm<<<196, 256, 0, stream>>>(x2, g1W, dis, h1d);
    wraw_pass<<<NBKT, 256, 0, stream>>>(bufR, gcurR, dis, wraw);
    gather_pass<<<NBKT, 256, 0, stream>>>(bufC, gcurC, dis, wraw, h1d, g1b, svec);
    finalize_kernel<<<1, 64, 0, stream>>>(bnsum, bnsumsq, gamma, beta, svec,
                                          g2W, g2b, fc1W, fc1b, fc2W, fc2b,
                                          scale, shift, vdnn, cons);
    out_kernel<<<4096, 256, 0, stream>>>(hdnn, scale, shift, vdnn, cons,
                                         (float*)d_out);
}